// Round 7
// baseline (198.732 us; speedup 1.0000x reference)
//
#include <hip/hip_runtime.h>

typedef __attribute__((ext_vector_type(8))) short short8;
typedef __attribute__((ext_vector_type(4))) float f32x4;

#define KDIM 512
#define NCT  30            // conv n-tiles (480 cols; chunk padded to 32 tiles)
// ---- dynamic LDS map (148480 B total) ----
#define SLOT      32768    // conv/PW ring slot bytes (conv ring: 4 slots = 131072)
#define W1_OFF    0        // W1 resident (57344 B), staged during conv epilogue
#define W2_OFF    57344    // W2 resident (57344 B), staged during gemm2
#define CB_OFF    93952    // epilogue dump buffer (20736 B), dies before gemm2
#define HT_OFF    114688   // h tile, 128 rows x 132 shorts (33792 B)
#define LDS_TOTAL 148480
#define HT_STRIDE 132      // shorts (264 B row stride, conflict-free)
#define CBS 81             // Cb stride in floats (max 5-tile phase + 1)

// ---- bf16 helpers (RNE) ----
__device__ __forceinline__ unsigned short f2bf(float x) {
    unsigned u = __float_as_uint(x);
    return (unsigned short)((u + 0x7FFFu + ((u >> 16) & 1u)) >> 16);
}
__device__ __forceinline__ float bf2f(unsigned short h) {
    return __uint_as_float(((unsigned)h) << 16);
}

// ---- async global->LDS 16B stage: g is per-lane, l is wave-uniform base ----
__device__ __forceinline__ void stage16(const void* g, void* l, int lane) {
    __builtin_amdgcn_global_load_lds(
        (const __attribute__((address_space(1))) unsigned int*)g,
        (__attribute__((address_space(3))) unsigned int*)l, 16, 0, 0);
}

// ===========================================================================
// Prep: swizzle all weights into MFMA B-fragment order (bf16).
// B-frag (16x16x32): lane l = kq*16+c0 holds B[k0+kq*8+i][n0+c0], i=0..7.
// WC  : 16 chunks x 16384 shorts (32 tiles, 30 valid) -- 32KB staging chunks.
// W1/W2: TIGHT 4 kq-chunks x 14 tiles x 512 shorts = 57344 B total each.
// PW  : TIGHT 4 kq-chunks x 32 tiles x 512 shorts = 131072 B (4 x 32KB).
// ===========================================================================
__global__ void prep_kernel(const float* __restrict__ w1, const float* __restrict__ w2,
                            const float* __restrict__ w3, const float* __restrict__ w4,
                            const float* __restrict__ w5, const float* __restrict__ w6,
                            const float* __restrict__ w7, const float* __restrict__ hw1,
                            const float* __restrict__ hw2, const float* __restrict__ pw,
                            unsigned short* __restrict__ WC, unsigned short* __restrict__ W1s,
                            unsigned short* __restrict__ W2s, unsigned short* __restrict__ Ps) {
    int gid = blockIdx.x * 256 + threadIdx.x;
    if (gid < 245760) {                      // conv: 512*480
        int k = gid / 480, col = gid % 480;
        const float* wp; int cbnd, NP, C, W;
        if (col < 32)       { wp = w1; cbnd = 0;   NP = 8; C = 4;  W = 1; }
        else if (col < 96)  { wp = w2; cbnd = 32;  NP = 7; C = 8;  W = 2; }
        else if (col < 176) { wp = w3; cbnd = 96;  NP = 6; C = 12; W = 3; }
        else if (col < 256) { wp = w4; cbnd = 176; NP = 5; C = 16; W = 4; }
        else if (col < 336) { wp = w5; cbnd = 256; NP = 4; C = 20; W = 5; }
        else if (col < 416) { wp = w6; cbnd = 336; NP = 3; C = 24; W = 6; }
        else                { wp = w7; cbnd = 416; NP = 2; C = 28; W = 7; }
        int c2 = col - cbnd, oc = c2 / NP, p = c2 - oc * NP;
        int j = k >> 6, e = k & 63, dk = j - p;
        float v = 0.f;
        if (oc < C && dk >= 0 && dk < W) v = wp[(oc * 64 + e) * W + dk];
        int q = k >> 5, kr = k & 31;
        WC[q * 16384 + ((col >> 4) * 64 + ((kr >> 3) * 16 + (col & 15))) * 8 + (kr & 7)] = f2bf(v);
    } else if (gid < 245760 + 57344) {       // highway: 2 x (128*224)
        int x = gid - 245760;
        const float* src = (x < 28672) ? hw1 : hw2;
        unsigned short* dst = (x < 28672) ? W1s : W2s;
        if (x >= 28672) x -= 28672;
        int k = x / 224, n = x % 224;
        float v = (k < 112) ? src[n * 112 + k] : 0.f;
        int q = k >> 5, kr = k & 31;
        dst[(q * 14 + (n >> 4)) * 512 + ((kr >> 3) * 16 + (n & 15)) * 8 + (kr & 7)] = f2bf(v);
    } else if (gid < 245760 + 57344 + 65536) { // proj: 128*512
        int x = gid - 303104;
        int k = x / 512, n = x % 512;
        float v = (k < 112) ? pw[n * 112 + k] : 0.f;
        int q = k >> 5, kr = k & 31;
        Ps[(q * 32 + (n >> 4)) * 512 + ((kr >> 3) * 16 + (n & 15)) * 8 + (kr & 7)] = f2bf(v);
    }
}

// ===========================================================================
// Fused kernel: 512 thr / 8 waves / 128 rows / 256 blocks (1 per CU).
// Conv: 4-deep 32KB ring, depth-2 prefetch, ONE barrier per chunk.
//   Between barrier(q) and barrier(q+1) the live slots are q&3 (readers),
//   (q+1)&3,(q+2)&3 (landings), (q+3)&3 (new stage) — all distinct mod 4.
//   A 3-slot ring is RACY here: (q+3)%3==q%3 (R5 failure, absmax 0.35).
// Tail: W1 staged under conv epilogue; W2 under gemm2; PW c0 under gemm3;
//   PW c1-3 under gemm4 (counted vmcnt). gemm2/gemm3 barrier-free.
// ===========================================================================
template <int T0, int NT>
__device__ __forceinline__ void dump_phase(float* Cb, const f32x4* acc, int w4, int lane) {
    int r0 = w4 * 16 + ((lane >> 4) * 4);
    int c0 = lane & 15;
#pragma unroll
    for (int tt = 0; tt < NT; ++tt)
#pragma unroll
        for (int r = 0; r < 4; ++r)
            Cb[(r0 + r) * CBS + tt * 16 + c0] = acc[T0 + tt][r];
}

__device__ __forceinline__ void reduce_rows(const float* Cb, unsigned short* ht, int tid,
                                            int c, int NP, int choff, const float* cb) {
    for (int idx = tid; idx < 64 * c; idx += 512) {
        int row = idx & 63, oc = idx >> 6;
        const float* src = Cb + row * CBS + oc * NP;
        float m = src[0];
        for (int k = 1; k < NP; ++k) m = fmaxf(m, src[k]);
        ht[row * HT_STRIDE + choff + oc] = f2bf(fmaxf(m + cb[oc], 0.f));
    }
}

template <int T0, int NT>
__device__ __forceinline__ void epi_phase(char* smb, const f32x4* acc, int tid, int wave, int lane,
                                          int c, int NP, int choff, const float* cb) {
    float* Cb = (float*)(smb + CB_OFF);
    unsigned short* ht = (unsigned short*)(smb + HT_OFF);
#pragma unroll
    for (int g = 0; g < 2; ++g) {
        if ((wave >> 2) == g) dump_phase<T0, NT>(Cb, acc, wave & 3, lane);
        asm volatile("s_waitcnt lgkmcnt(0)" ::: "memory");
        __builtin_amdgcn_s_barrier();
        reduce_rows(Cb, ht + g * 64 * HT_STRIDE, tid, c, NP, choff, cb);
        asm volatile("s_waitcnt lgkmcnt(0)" ::: "memory");
        __builtin_amdgcn_s_barrier();
    }
}

__global__ __launch_bounds__(512, 2) void fused_kernel(
        const float* __restrict__ feat, const unsigned short* __restrict__ WC,
        const float* cb0, const float* cb1, const float* cb2, const float* cb3,
        const float* cb4, const float* cb5, const float* cb6,
        const unsigned short* __restrict__ W1, const unsigned short* __restrict__ W2,
        const unsigned short* __restrict__ PW,
        const float* __restrict__ hb1, const float* __restrict__ hb2,
        const float* __restrict__ pb, float* __restrict__ out) {
    extern __shared__ __align__(16) char sm[];
    const int tid = threadIdx.x, lane = tid & 63, wave = tid >> 6;
    const int c0 = lane & 15, kq = lane >> 4;
    const int m0 = blockIdx.x * 128;
    f32x4 zero = {0.f, 0.f, 0.f, 0.f};
    unsigned short* ht = (unsigned short*)(sm + HT_OFF);

    // ---------------- conv GEMM: A-frags (16 k-chunks) in registers ----------------
    const float* arow = feat + (size_t)(m0 + wave * 16 + c0) * KDIM + kq * 8;
    short8 af[16];
#pragma unroll
    for (int q = 0; q < 16; ++q) {
        float t[8];
        *(float4*)(t)     = *(const float4*)(arow + q * 32);
        *(float4*)(t + 4) = *(const float4*)(arow + q * 32 + 4);
        short8 v;
#pragma unroll
        for (int i = 0; i < 8; ++i) v[i] = (short)f2bf(t[i]);
        af[q] = v;
    }

    f32x4 acc[NCT];
#pragma unroll
    for (int t = 0; t < NCT; ++t) acc[t] = zero;

    // prologue: chunks 0,1 into slots 0,1 (4 loads/thread each)
    for (int i = tid; i < 2048; i += 512)
        stage16(WC + i * 8, sm + (i - lane) * 16, lane);
    for (int i = tid; i < 2048; i += 512)
        stage16(WC + 16384 + i * 8, sm + SLOT + (i - lane) * 16, lane);

#pragma unroll
    for (int q = 0; q < 16; ++q) {
        if (q < 14) {
            const unsigned short* src = WC + (q + 2) * 16384;
            char* dst = sm + ((q + 2) & 3) * SLOT;
            for (int i = tid; i < 2048; i += 512)
                stage16(src + i * 8, dst + (i - lane) * 16, lane);
            asm volatile("s_waitcnt vmcnt(8)" ::: "memory");   // chunk q landed; q+1,q+2 in flight
        } else if (q == 14) {
            asm volatile("s_waitcnt vmcnt(4)" ::: "memory");   // chunk 14 landed; 15 in flight
        } else {
            asm volatile("s_waitcnt vmcnt(0)" ::: "memory");
        }
        __builtin_amdgcn_s_barrier();
        const char* bb = sm + (q & 3) * SLOT;
#pragma unroll
        for (int t = 0; t < NCT; ++t) {
            short8 b = *(const short8*)(bb + (t * 64 + lane) * 16);
            acc[t] = __builtin_amdgcn_mfma_f32_16x16x32_bf16(af[q], b, acc[t], 0, 0, 0);
        }
        // single barrier per iter is safe with the 4-slot ring (see header)
    }
    asm volatile("s_waitcnt lgkmcnt(0)" ::: "memory");
    __builtin_amdgcn_s_barrier();                              // ring dead block-wide

    // ---------------- stage W1 (resident) under the conv epilogue ----------------
    for (int i = tid; i < 3584; i += 512)                      // 7 loads/thread
        stage16(W1 + i * 8, sm + W1_OFF + (i - lane) * 16, lane);

    // zero ht K-pad cols 112..127 (ring dead; separated from a2 reads by epi barriers)
    for (int i = tid; i < 2048; i += 512)
        ht[(i >> 4) * HT_STRIDE + 112 + (i & 15)] = 0;

    // ---------------- conv epilogue: 7 filter-aligned phases x 2 row-groups ----------------
    epi_phase<0, 2>(sm, acc, tid, wave, lane, 4, 8, 0, cb0);
    epi_phase<2, 4>(sm, acc, tid, wave, lane, 8, 7, 4, cb1);
    epi_phase<6, 5>(sm, acc, tid, wave, lane, 12, 6, 12, cb2);
    epi_phase<11, 5>(sm, acc, tid, wave, lane, 16, 5, 24, cb3);
    epi_phase<16, 5>(sm, acc, tid, wave, lane, 20, 4, 40, cb4);
    epi_phase<21, 5>(sm, acc, tid, wave, lane, 24, 3, 60, cb5);
    epi_phase<26, 4>(sm, acc, tid, wave, lane, 28, 2, 84, cb6);
    // ht complete & visible (last epi barrier); Cb dead

    // ---------------- GEMM2 (highway1): W1 resident, barrier-free ----------------
    short8 a2[4];
#pragma unroll
    for (int q = 0; q < 4; ++q)
        a2[q] = *(const short8*)((const char*)ht + (wave * 16 + c0) * (HT_STRIDE * 2) + q * 64 + kq * 16);

    // stage W2 (resident) under gemm2
    for (int i = tid; i < 3584; i += 512)
        stage16(W2 + i * 8, sm + W2_OFF + (i - lane) * 16, lane);
    asm volatile("s_waitcnt vmcnt(7)" ::: "memory");           // W1 landed (W2's 7 in flight)
    __builtin_amdgcn_s_barrier();

    f32x4 acc2[14];
#pragma unroll
    for (int t = 0; t < 14; ++t) acc2[t] = zero;
#pragma unroll
    for (int q = 0; q < 4; ++q)
#pragma unroll
        for (int t = 0; t < 14; ++t) {
            short8 b = *(const short8*)(sm + W1_OFF + (q * 14 + t) * 1024 + lane * 16);
            acc2[t] = __builtin_amdgcn_mfma_f32_16x16x32_bf16(a2[q], b, acc2[t], 0, 0, 0);
        }

    // epilogue2 -> ht in place (wave-private rows, no barrier)
#pragma unroll
    for (int t = 0; t < 7; ++t) {
        float bp = hb1[t * 16 + c0], bg = hb1[112 + t * 16 + c0];
#pragma unroll
        for (int r = 0; r < 4; ++r) {
            int row = wave * 16 + kq * 4 + r;
            int col = t * 16 + c0;
            float px = acc2[t][r] + bp;
            float gt = acc2[t + 7][r] + bg;
            float g = 1.f / (1.f + __expf(-gt));
            float hres = bf2f(ht[row * HT_STRIDE + col]);
            ht[row * HT_STRIDE + col] = f2bf(g * hres + (1.f - g) * fmaxf(px, 0.f));
        }
    }

    // A3 frags (own-wave rows; in-wave DS ordering suffices)
    short8 a3[4];
#pragma unroll
    for (int q = 0; q < 4; ++q)
        a3[q] = *(const short8*)((const char*)ht + (wave * 16 + c0) * (HT_STRIDE * 2) + q * 64 + kq * 16);

    asm volatile("s_waitcnt vmcnt(0)" ::: "memory");           // W2 landed
    __builtin_amdgcn_s_barrier();                              // W2 visible; W1 dead

    // stage PW chunk 0 under gemm3 (into dead W1 region = slot 0)
    for (int i = tid; i < 2048; i += 512)
        stage16(PW + i * 8, sm + (i - lane) * 16, lane);

    // ---------------- GEMM3 (highway2): W2 resident, barrier-free ----------------
    f32x4 acc3[14];
#pragma unroll
    for (int t = 0; t < 14; ++t) acc3[t] = zero;
#pragma unroll
    for (int q = 0; q < 4; ++q)
#pragma unroll
        for (int t = 0; t < 14; ++t) {
            short8 b = *(const short8*)(sm + W2_OFF + (q * 14 + t) * 1024 + lane * 16);
            acc3[t] = __builtin_amdgcn_mfma_f32_16x16x32_bf16(a3[q], b, acc3[t], 0, 0, 0);
        }

    // epilogue3 -> ht in place (wave-private)
#pragma unroll
    for (int t = 0; t < 7; ++t) {
        float bp = hb2[t * 16 + c0], bg = hb2[112 + t * 16 + c0];
#pragma unroll
        for (int r = 0; r < 4; ++r) {
            int row = wave * 16 + kq * 4 + r;
            int col = t * 16 + c0;
            float px = acc3[t][r] + bp;
            float gt = acc3[t + 7][r] + bg;
            float g = 1.f / (1.f + __expf(-gt));
            float hres = bf2f(ht[row * HT_STRIDE + col]);
            ht[row * HT_STRIDE + col] = f2bf(g * hres + (1.f - g) * fmaxf(px, 0.f));
        }
    }

    // A4 frags (own-wave rows)
    short8 a4[4];
#pragma unroll
    for (int q = 0; q < 4; ++q)
        a4[q] = *(const short8*)((const char*)ht + (wave * 16 + c0) * (HT_STRIDE * 2) + q * 64 + kq * 16);

    asm volatile("s_waitcnt lgkmcnt(0)" ::: "memory");
    __builtin_amdgcn_s_barrier();                              // ht & W2 dead block-wide

    // stage PW chunks 1..3 into slots 1..3 (overlay dead W1/W2/Cb/ht regions)
#pragma unroll
    for (int c = 1; c < 4; ++c)
        for (int i = tid; i < 2048; i += 512)
            stage16(PW + c * 16384 + i * 8, sm + c * SLOT + (i - lane) * 16, lane);

    // ---------------- GEMM4 (proj): 4 k-chunks, counted vmcnt ----------------
    f32x4 acc4[32];
#pragma unroll
    for (int t = 0; t < 32; ++t) acc4[t] = zero;
#pragma unroll
    for (int c = 0; c < 4; ++c) {
        if (c == 0)      asm volatile("s_waitcnt vmcnt(12)" ::: "memory");
        else if (c == 1) asm volatile("s_waitcnt vmcnt(8)" ::: "memory");
        else if (c == 2) asm volatile("s_waitcnt vmcnt(4)" ::: "memory");
        else             asm volatile("s_waitcnt vmcnt(0)" ::: "memory");
        __builtin_amdgcn_s_barrier();
        const char* bb = sm + c * SLOT;
#pragma unroll
        for (int tt = 0; tt < 32; ++tt) {
            short8 b = *(const short8*)(bb + tt * 1024 + lane * 16);
            acc4[tt] = __builtin_amdgcn_mfma_f32_16x16x32_bf16(a4[c], b, acc4[tt], 0, 0, 0);
        }
    }

    // ---------------- epilogue4: +bias, direct coalesced stores ----------------
    const int rbase = m0 + wave * 16 + kq * 4;
#pragma unroll
    for (int tt = 0; tt < 32; ++tt) {
        float b = pb[tt * 16 + c0];
#pragma unroll
        for (int r = 0; r < 4; ++r)
            out[(size_t)(rbase + r) * 512 + tt * 16 + c0] = acc4[tt][r] + b;
    }
}

// ===========================================================================
extern "C" void kernel_launch(void* const* d_in, const int* in_sizes, int n_in,
                              void* d_out, int out_size, void* d_ws, size_t ws_size,
                              hipStream_t stream) {
    const float* feat = (const float*)d_in[0];
    const float* cw[7];
    const float* cb[7];
    for (int f = 0; f < 7; ++f) {
        cw[f] = (const float*)d_in[1 + 2 * f];
        cb[f] = (const float*)d_in[2 + 2 * f];
    }
    const float* hw_w1 = (const float*)d_in[15];
    const float* hw_b1 = (const float*)d_in[16];
    const float* hw_w2 = (const float*)d_in[17];
    const float* hw_b2 = (const float*)d_in[18];
    const float* pw    = (const float*)d_in[19];
    const float* pb    = (const float*)d_in[20];
    float* out = (float*)d_out;

    char* ws = (char*)d_ws;
    unsigned short* WC  = (unsigned short*)ws;                  // 524,288 B (16 x 32KB)
    unsigned short* W1s = (unsigned short*)(ws + 524288);       //  57,344 B tight
    unsigned short* W2s = (unsigned short*)(ws + 581632);       //  57,344 B tight
    unsigned short* Ps  = (unsigned short*)(ws + 638976);       // 131,072 B tight (4 x 32KB)

    hipFuncSetAttribute((const void*)fused_kernel,
                        hipFuncAttributeMaxDynamicSharedMemorySize, LDS_TOTAL);

    prep_kernel<<<1440, 256, 0, stream>>>(cw[0], cw[1], cw[2], cw[3], cw[4], cw[5], cw[6],
                                          hw_w1, hw_w2, pw, WC, W1s, W2s, Ps);
    fused_kernel<<<256, 512, LDS_TOTAL, stream>>>(feat, WC, cb[0], cb[1], cb[2], cb[3], cb[4],
                                                  cb[5], cb[6], W1s, W2s, Ps, hw_b1, hw_b2, pb, out);
}

// Round 8
// 192.711 us; speedup vs baseline: 1.0312x; 1.0312x over previous
//
#include <hip/hip_runtime.h>

typedef __attribute__((ext_vector_type(8))) short short8;
typedef __attribute__((ext_vector_type(4))) float f32x4;

#define KDIM 512
#define NCT  30          // conv n-tiles (480 cols, padded to 32 tiles in chunk)
#define BCHUNK 32768     // padded conv B chunk bytes (32 tiles; 30 valid)

// ---- bf16 helpers (RNE) ----
__device__ __forceinline__ unsigned short f2bf(float x) {
    unsigned u = __float_as_uint(x);
    return (unsigned short)((u + 0x7FFFu + ((u >> 16) & 1u)) >> 16);
}
__device__ __forceinline__ float bf2f(unsigned short h) {
    return __uint_as_float(((unsigned)h) << 16);
}

// ---- async global->LDS 16B stage: g is per-lane, l is wave-uniform base ----
__device__ __forceinline__ void stage16(const void* g, void* l, int lane) {
    __builtin_amdgcn_global_load_lds(
        (const __attribute__((address_space(1))) unsigned int*)g,
        (__attribute__((address_space(3))) unsigned int*)l, 16, 0, 0);
}

// ===========================================================================
// Prep v2: coalesced. Each thread emits the 8 contiguous shorts of one frag
// group (innermost index kr&7 == k&7 within an 8-aligned k-group) as ONE
// short8 (16B) store; consecutive threads write consecutive 16B. 46080
// threads total (was 368640 w/ scattered 2B stores).
// Group algebra (k = kb*8+i): q=kb>>2, kr>>3=kb&3, kr&7=i, j=kb>>3,
// e=(kb&7)*8+i — all verified identical to the per-element prep.
// Layouts (consumed by fused): WC 16 chunks x 16384 shorts (32 tiles, 30
// valid); W1/W2 4 chunks x 8192 shorts (16 tiles, 14 valid); Ps 8 chunks
// x 8192 shorts (tiles (q*32+nt)).
// ===========================================================================
__global__ __launch_bounds__(256) void prep_kernel(
        const float* __restrict__ w1, const float* __restrict__ w2,
        const float* __restrict__ w3, const float* __restrict__ w4,
        const float* __restrict__ w5, const float* __restrict__ w6,
        const float* __restrict__ w7, const float* __restrict__ hw1,
        const float* __restrict__ hw2, const float* __restrict__ pw,
        unsigned short* __restrict__ WC, unsigned short* __restrict__ W1s,
        unsigned short* __restrict__ W2s, unsigned short* __restrict__ Ps) {
    int gid = blockIdx.x * 256 + threadIdx.x;
    if (gid < 30720) {                        // conv: 64 k-groups x 480 cols
        int kb = gid / 480, col = gid % 480;
        const float* wp; int cbnd, NP, C, W;
        if (col < 32)       { wp = w1; cbnd = 0;   NP = 8; C = 4;  W = 1; }
        else if (col < 96)  { wp = w2; cbnd = 32;  NP = 7; C = 8;  W = 2; }
        else if (col < 176) { wp = w3; cbnd = 96;  NP = 6; C = 12; W = 3; }
        else if (col < 256) { wp = w4; cbnd = 176; NP = 5; C = 16; W = 4; }
        else if (col < 336) { wp = w5; cbnd = 256; NP = 4; C = 20; W = 5; }
        else if (col < 416) { wp = w6; cbnd = 336; NP = 3; C = 24; W = 6; }
        else                { wp = w7; cbnd = 416; NP = 2; C = 28; W = 7; }
        int c2 = col - cbnd, oc = c2 / NP, p = c2 - oc * NP;
        int j = kb >> 3, dk = j - p, e0 = (kb & 7) * 8;
        bool valid = (oc < C) && (dk >= 0) && (dk < W);
        short8 v8;
#pragma unroll
        for (int i = 0; i < 8; ++i) {
            float v = valid ? wp[(oc * 64 + e0 + i) * W + dk] : 0.f;
            v8[i] = (short)f2bf(v);
        }
        int q = kb >> 2, krh = kb & 3;
        *(short8*)(WC + (size_t)q * 16384 + ((col >> 4) * 64 + krh * 16 + (col & 15)) * 8) = v8;
    } else if (gid < 30720 + 7168) {          // highway: 2 x (16 k-groups x 224 n)
        int x = gid - 30720;
        const float* src = (x < 3584) ? hw1 : hw2;
        unsigned short* dst = (x < 3584) ? W1s : W2s;
        if (x >= 3584) x -= 3584;
        int kb = x / 224, n = x % 224, k0 = kb * 8;
        short8 v8;
#pragma unroll
        for (int i = 0; i < 8; ++i) {
            float v = (k0 + i < 112) ? src[n * 112 + k0 + i] : 0.f;
            v8[i] = (short)f2bf(v);
        }
        int q = kb >> 2, krh = kb & 3;
        *(short8*)(dst + q * 8192 + ((n >> 4) * 64 + krh * 16 + (n & 15)) * 8) = v8;
    } else if (gid < 30720 + 7168 + 8192) {   // proj: 16 k-groups x 512 n
        int x = gid - 37888;
        int kb = x / 512, n = x % 512, k0 = kb * 8;
        short8 v8;
#pragma unroll
        for (int i = 0; i < 8; ++i) {
            float v = (k0 + i < 112) ? pw[n * 112 + k0 + i] : 0.f;
            v8[i] = (short)f2bf(v);
        }
        int q = kb >> 2, krh = kb & 3;
        *(short8*)(Ps + ((q * 32 + (n >> 4)) * 64 + krh * 16 + (n & 15)) * 8) = v8;
    }
}

// ===========================================================================
// Fused kernel (verbatim best-verified R3 structure, fused ~71 us):
// conv GEMM + max/relu + highway1 + highway2 + proj; 256 thr / 4 waves /
// 64 rows / 512 blocks (2 per CU). Counted-vmcnt dbuf staging throughout.
// ===========================================================================
template <int T0, int NT>
__device__ __forceinline__ void dump_phase(float* Cb, const f32x4* acc, int wave, int lane) {
    int r0 = wave * 16 + ((lane >> 4) * 4);
    int c0 = lane & 15;
#pragma unroll
    for (int tt = 0; tt < NT; ++tt)
#pragma unroll
        for (int r = 0; r < 4; ++r)
            Cb[(r0 + r) * 161 + tt * 16 + c0] = acc[T0 + tt][r];
}

__device__ void reduce_phase(const float* Cb, unsigned short* ht, int tid,
                             int cA, int NPA, int choffA, int colbA, const float* cbA,
                             int cB, int NPB, int choffB, int colbB, const float* cbB) {
    int noc = cA + cB;
    for (int idx = tid; idx < 64 * noc; idx += 256) {
        int row = idx & 63, ocp = idx >> 6;
        bool isB = ocp >= cA;
        int oc = isB ? ocp - cA : ocp;
        int NP = isB ? NPB : NPA;
        int colb = isB ? colbB : colbA;
        int choff = isB ? choffB : choffA;
        const float* cb = isB ? cbB : cbA;
        const float* src = Cb + row * 161 + colb + oc * NP;
        float m = src[0];
        for (int k = 1; k < NP; ++k) m = fmaxf(m, src[k]);
        float v = fmaxf(m + cb[oc], 0.f);
        ht[row * 136 + choff + oc] = f2bf(v);
    }
}

__global__ __launch_bounds__(256, 2) void fused_kernel(
        const float* __restrict__ feat, const unsigned short* __restrict__ WC,
        const float* cb0, const float* cb1, const float* cb2, const float* cb3,
        const float* cb4, const float* cb5, const float* cb6,
        const unsigned short* __restrict__ W1, const unsigned short* __restrict__ W2,
        const unsigned short* __restrict__ PW,
        const float* __restrict__ hb1, const float* __restrict__ hb2,
        const float* __restrict__ pb, float* __restrict__ out) {
    __shared__ __align__(16) char sm[65536];
    const int tid = threadIdx.x, lane = tid & 63, wave = tid >> 6;
    const int c0 = lane & 15, kq = lane >> 4;
    const int m0 = blockIdx.x * 64;
    f32x4 zero = {0.f, 0.f, 0.f, 0.f};

    // ---------------- conv GEMM ----------------
    const float* arow = feat + (size_t)(m0 + wave * 16 + c0) * KDIM + kq * 8;
    short8 af[16];
#pragma unroll
    for (int q = 0; q < 16; ++q) {
        float t[8];
        *(float4*)(t)     = *(const float4*)(arow + q * 32);
        *(float4*)(t + 4) = *(const float4*)(arow + q * 32 + 4);
        short8 v;
#pragma unroll
        for (int i = 0; i < 8; ++i) v[i] = (short)f2bf(t[i]);
        af[q] = v;
    }

    f32x4 acc[NCT];
#pragma unroll
    for (int t = 0; t < NCT; ++t) acc[t] = zero;

    // prologue: stage chunk 0 into buf 0
    for (int i = tid; i < 2048; i += 256)
        stage16(WC + i * 8, sm + (i - lane) * 16, lane);

#pragma unroll
    for (int q = 0; q < 16; ++q) {
        if (q < 15) {
            const unsigned short* src = WC + (q + 1) * 16384;
            char* dst = sm + ((q + 1) & 1) * BCHUNK;
            for (int i = tid; i < 2048; i += 256)
                stage16(src + i * 8, dst + (i - lane) * 16, lane);
            asm volatile("s_waitcnt vmcnt(8)" ::: "memory");   // chunk q landed; q+1 in flight
        } else {
            asm volatile("s_waitcnt vmcnt(0)" ::: "memory");
        }
        __builtin_amdgcn_s_barrier();
        const char* bb = sm + (q & 1) * BCHUNK;
        __builtin_amdgcn_s_setprio(1);
#pragma unroll
        for (int t = 0; t < NCT; ++t) {
            short8 b = *(const short8*)(bb + (t * 64 + lane) * 16);
            acc[t] = __builtin_amdgcn_mfma_f32_16x16x32_bf16(af[q], b, acc[t], 0, 0, 0);
        }
        __builtin_amdgcn_s_setprio(0);
        asm volatile("s_waitcnt lgkmcnt(0)" ::: "memory");     // reads of buf done
        __builtin_amdgcn_s_barrier();                          // safe to restage next iter
    }

    // ---------------- conv epilogue (max/bias/relu -> ht in LDS) ----------------
    float* Cb = (float*)sm;
    unsigned short* ht = (unsigned short*)(sm + 41216);   // 64 rows x 136 shorts
    __syncthreads();
    for (int i = tid; i < 1024; i += 256)                 // zero K-pad cols 112..127
        ht[(i >> 4) * 136 + 112 + (i & 15)] = 0;
    dump_phase<0, 6>(Cb, acc, wave, lane);
    __syncthreads();
    reduce_phase(Cb, ht, tid, 4, 8, 0, 0, cb0, 8, 7, 4, 32, cb1);
    __syncthreads();
    dump_phase<6, 10>(Cb, acc, wave, lane);
    __syncthreads();
    reduce_phase(Cb, ht, tid, 12, 6, 12, 0, cb2, 16, 5, 24, 80, cb3);
    __syncthreads();
    dump_phase<16, 10>(Cb, acc, wave, lane);
    __syncthreads();
    reduce_phase(Cb, ht, tid, 20, 4, 40, 0, cb4, 24, 3, 60, 80, cb5);
    __syncthreads();
    dump_phase<26, 4>(Cb, acc, wave, lane);
    __syncthreads();
    reduce_phase(Cb, ht, tid, 28, 2, 84, 0, cb6, 0, 1, 0, 0, cb6);
    __syncthreads();                                      // ht complete

    // ---------------- GEMM2 (highway1): 4 x 16KB dbuf chunks ----------------
    char* wb = sm;                                        // 2 x 16384
    short8 a2[4];
#pragma unroll
    for (int q = 0; q < 4; ++q)
        a2[q] = *(const short8*)((const char*)ht + (wave * 16 + c0) * 272 + q * 64 + kq * 16);
    for (int i = tid; i < 1024; i += 256)                 // stage W1 chunk 0
        stage16(W1 + i * 8, wb + (i - lane) * 16, lane);

    f32x4 acc2[14];
#pragma unroll
    for (int t = 0; t < 14; ++t) acc2[t] = zero;
#pragma unroll
    for (int q = 0; q < 4; ++q) {
        if (q < 3) {
            const unsigned short* src = W1 + (q + 1) * 8192;
            char* dst = wb + ((q + 1) & 1) * 16384;
            for (int i = tid; i < 1024; i += 256)
                stage16(src + i * 8, dst + (i - lane) * 16, lane);
        } else {
            // cross-prefetch W2 chunk 0 into wb buf0 (this iter reads buf1)
            for (int i = tid; i < 1024; i += 256)
                stage16(W2 + i * 8, wb + (i - lane) * 16, lane);
        }
        asm volatile("s_waitcnt vmcnt(4)" ::: "memory");
        __builtin_amdgcn_s_barrier();
        const char* bb = wb + (q & 1) * 16384;
#pragma unroll
        for (int t = 0; t < 14; ++t) {
            short8 b = *(const short8*)(bb + (t * 64 + lane) * 16);
            acc2[t] = __builtin_amdgcn_mfma_f32_16x16x32_bf16(a2[q], b, acc2[t], 0, 0, 0);
        }
        asm volatile("s_waitcnt lgkmcnt(0)" ::: "memory");
        __builtin_amdgcn_s_barrier();
    }

    // epilogue2 -> ht in place (wave-local rows; same-wave DS ordering)
#pragma unroll
    for (int t = 0; t < 7; ++t) {
        float bp = hb1[t * 16 + c0], bg = hb1[112 + t * 16 + c0];
#pragma unroll
        for (int r = 0; r < 4; ++r) {
            int row = wave * 16 + kq * 4 + r;
            int col = t * 16 + c0;
            float px = acc2[t][r] + bp;
            float gt = acc2[t + 7][r] + bg;
            float g = 1.f / (1.f + __expf(-gt));
            float hres = bf2f(ht[row * 136 + col]);
            ht[row * 136 + col] = f2bf(g * hres + (1.f - g) * fmaxf(px, 0.f));
        }
    }

    // ---------------- GEMM3 (highway2): W2 chunks (c0 already in flight) ----------------
    short8 a3[4];
#pragma unroll
    for (int q = 0; q < 4; ++q)
        a3[q] = *(const short8*)((const char*)ht + (wave * 16 + c0) * 272 + q * 64 + kq * 16);

    f32x4 acc3[14];
#pragma unroll
    for (int t = 0; t < 14; ++t) acc3[t] = zero;
#pragma unroll
    for (int q = 0; q < 4; ++q) {
        if (q < 3) {
            const unsigned short* src = W2 + (q + 1) * 8192;
            char* dst = wb + ((q + 1) & 1) * 16384;
            for (int i = tid; i < 1024; i += 256)
                stage16(src + i * 8, dst + (i - lane) * 16, lane);
        } else {
            // cross-prefetch PW chunk 0 into pwb buf0 = wb buf0 (this iter reads buf1)
            for (int i = tid; i < 1024; i += 256)
                stage16(PW + i * 8, wb + (i - lane) * 16, lane);
        }
        asm volatile("s_waitcnt vmcnt(4)" ::: "memory");
        __builtin_amdgcn_s_barrier();
        const char* bb = wb + (q & 1) * 16384;
#pragma unroll
        for (int t = 0; t < 14; ++t) {
            short8 b = *(const short8*)(bb + (t * 64 + lane) * 16);
            acc3[t] = __builtin_amdgcn_mfma_f32_16x16x32_bf16(a3[q], b, acc3[t], 0, 0, 0);
        }
        asm volatile("s_waitcnt lgkmcnt(0)" ::: "memory");
        __builtin_amdgcn_s_barrier();
    }

    // epilogue3 -> ht in place (PW chunk 0 latency hides under this)
#pragma unroll
    for (int t = 0; t < 7; ++t) {
        float bp = hb2[t * 16 + c0], bg = hb2[112 + t * 16 + c0];
#pragma unroll
        for (int r = 0; r < 4; ++r) {
            int row = wave * 16 + kq * 4 + r;
            int col = t * 16 + c0;
            float px = acc3[t][r] + bp;
            float gt = acc3[t + 7][r] + bg;
            float g = 1.f / (1.f + __expf(-gt));
            float hres = bf2f(ht[row * 136 + col]);
            ht[row * 136 + col] = f2bf(g * hres + (1.f - g) * fmaxf(px, 0.f));
        }
    }

    // ---------------- GEMM4 (proj): 8 x 16KB dbuf chunks ----------------
    short8 a4[4];
#pragma unroll
    for (int q = 0; q < 4; ++q)
        a4[q] = *(const short8*)((const char*)ht + (wave * 16 + c0) * 272 + q * 64 + kq * 16);

    char* pwb = sm;                                       // 2 x 16384 (buf0 = PW c0)
    f32x4 acc4[32];
#pragma unroll
    for (int t = 0; t < 32; ++t) acc4[t] = zero;
#pragma unroll
    for (int c = 0; c < 8; ++c) {
        if (c < 7) {
            const unsigned short* src = PW + (c + 1) * 8192;
            char* dst = pwb + ((c + 1) & 1) * 16384;
            for (int i = tid; i < 1024; i += 256)
                stage16(src + i * 8, dst + (i - lane) * 16, lane);
            asm volatile("s_waitcnt vmcnt(4)" ::: "memory");
        } else {
            asm volatile("s_waitcnt vmcnt(0)" ::: "memory");
        }
        __builtin_amdgcn_s_barrier();
        const char* bb = pwb + (c & 1) * 16384;
        __builtin_amdgcn_s_setprio(1);
#pragma unroll
        for (int tt = 0; tt < 16; ++tt) {
            short8 b = *(const short8*)(bb + (tt * 64 + lane) * 16);
            acc4[(c & 1) * 16 + tt] =
                __builtin_amdgcn_mfma_f32_16x16x32_bf16(a4[c >> 1], b, acc4[(c & 1) * 16 + tt], 0, 0, 0);
        }
        __builtin_amdgcn_s_setprio(0);
        asm volatile("s_waitcnt lgkmcnt(0)" ::: "memory");
        __builtin_amdgcn_s_barrier();
    }

    // ---------------- epilogue4: +bias, coalesced store via LDS transpose ----------------
    float* ot = (float*)sm;
#pragma unroll
    for (int half = 0; half < 2; ++half) {
        __syncthreads();
#pragma unroll
        for (int t16 = 0; t16 < 16; ++t16) {
            int col = (half * 16 + t16) * 16 + c0;
            float b = pb[col];
#pragma unroll
            for (int r = 0; r < 4; ++r)
                ot[(wave * 16 + kq * 4 + r) * 256 + t16 * 16 + c0] = acc4[half * 16 + t16][r] + b;
        }
        __syncthreads();
        for (int i = tid; i < 4096; i += 256) {
            int row = i >> 6, c = i & 63;
            *(float4*)(out + (size_t)(m0 + row) * 512 + half * 256 + c * 4) = ((const float4*)ot)[i];
        }
    }
}

// ===========================================================================
extern "C" void kernel_launch(void* const* d_in, const int* in_sizes, int n_in,
                              void* d_out, int out_size, void* d_ws, size_t ws_size,
                              hipStream_t stream) {
    const float* feat = (const float*)d_in[0];
    const float* cw[7];
    const float* cb[7];
    for (int f = 0; f < 7; ++f) {
        cw[f] = (const float*)d_in[1 + 2 * f];
        cb[f] = (const float*)d_in[2 + 2 * f];
    }
    const float* hw_w1 = (const float*)d_in[15];
    const float* hw_b1 = (const float*)d_in[16];
    const float* hw_w2 = (const float*)d_in[17];
    const float* hw_b2 = (const float*)d_in[18];
    const float* pw    = (const float*)d_in[19];
    const float* pb    = (const float*)d_in[20];
    float* out = (float*)d_out;

    char* ws = (char*)d_ws;
    unsigned short* WC  = (unsigned short*)ws;                  // 524,288 B (16 x 32KB padded)
    unsigned short* W1s = (unsigned short*)(ws + 524288);       //  65,536 B (4 x 16KB padded)
    unsigned short* W2s = (unsigned short*)(ws + 589824);       //  65,536 B
    unsigned short* Ps  = (unsigned short*)(ws + 655360);       // 131,072 B (8 x 16KB)

    prep_kernel<<<180, 256, 0, stream>>>(cw[0], cw[1], cw[2], cw[3], cw[4], cw[5], cw[6],
                                         hw_w1, hw_w2, pw, WC, W1s, W2s, Ps);
    fused_kernel<<<512, 256, 0, stream>>>(feat, WC, cb[0], cb[1], cb[2], cb[3], cb[4], cb[5], cb[6],
                                          W1s, W2s, Ps, hw_b1, hw_b2, pb, out);
}

// Round 9
// 189.408 us; speedup vs baseline: 1.0492x; 1.0174x over previous
//
#include <hip/hip_runtime.h>

typedef __attribute__((ext_vector_type(8))) short short8;
typedef __attribute__((ext_vector_type(4))) float f32x4;

#define KDIM 512
#define NCT  30          // conv n-tiles (480 cols, padded to 32 tiles in chunk)
#define BCHUNK 32768     // padded conv B chunk bytes (32 tiles; 30 valid)

// ---- bf16 helpers (RNE) ----
__device__ __forceinline__ unsigned short f2bf(float x) {
    unsigned u = __float_as_uint(x);
    return (unsigned short)((u + 0x7FFFu + ((u >> 16) & 1u)) >> 16);
}
__device__ __forceinline__ float bf2f(unsigned short h) {
    return __uint_as_float(((unsigned)h) << 16);
}

// ---- async global->LDS 16B stage: g is per-lane, l is wave-uniform base ----
__device__ __forceinline__ void stage16(const void* g, void* l, int lane) {
    __builtin_amdgcn_global_load_lds(
        (const __attribute__((address_space(1))) unsigned int*)g,
        (__attribute__((address_space(3))) unsigned int*)l, 16, 0, 0);
}

// ===========================================================================
// Prep: coalesced short8 frag emission (R8-verified) + zero-fill of W1/W2
// pad tiles 14,15 (read by the cg1 wave path, results discarded; zeroed for
// NaN hygiene). Layouts: WC 16 chunks x 16384 shorts (32 tiles, 30 valid);
// W1/W2 4 chunks x 8192 shorts (16 tiles: 14 valid + 2 zero); Ps 8 chunks
// x 8192 shorts (16 tiles each, all valid).
// ===========================================================================
__global__ __launch_bounds__(256) void prep_kernel(
        const float* __restrict__ w1, const float* __restrict__ w2,
        const float* __restrict__ w3, const float* __restrict__ w4,
        const float* __restrict__ w5, const float* __restrict__ w6,
        const float* __restrict__ w7, const float* __restrict__ hw1,
        const float* __restrict__ hw2, const float* __restrict__ pw,
        unsigned short* __restrict__ WC, unsigned short* __restrict__ W1s,
        unsigned short* __restrict__ W2s, unsigned short* __restrict__ Ps) {
    int gid = blockIdx.x * 256 + threadIdx.x;
    if (gid < 30720) {                        // conv: 64 k-groups x 480 cols
        int kb = gid / 480, col = gid % 480;
        const float* wp; int cbnd, NP, C, W;
        if (col < 32)       { wp = w1; cbnd = 0;   NP = 8; C = 4;  W = 1; }
        else if (col < 96)  { wp = w2; cbnd = 32;  NP = 7; C = 8;  W = 2; }
        else if (col < 176) { wp = w3; cbnd = 96;  NP = 6; C = 12; W = 3; }
        else if (col < 256) { wp = w4; cbnd = 176; NP = 5; C = 16; W = 4; }
        else if (col < 336) { wp = w5; cbnd = 256; NP = 4; C = 20; W = 5; }
        else if (col < 416) { wp = w6; cbnd = 336; NP = 3; C = 24; W = 6; }
        else                { wp = w7; cbnd = 416; NP = 2; C = 28; W = 7; }
        int c2 = col - cbnd, oc = c2 / NP, p = c2 - oc * NP;
        int j = kb >> 3, dk = j - p, e0 = (kb & 7) * 8;
        bool valid = (oc < C) && (dk >= 0) && (dk < W);
        short8 v8;
#pragma unroll
        for (int i = 0; i < 8; ++i) {
            float v = valid ? wp[(oc * 64 + e0 + i) * W + dk] : 0.f;
            v8[i] = (short)f2bf(v);
        }
        int q = kb >> 2, krh = kb & 3;
        *(short8*)(WC + (size_t)q * 16384 + ((col >> 4) * 64 + krh * 16 + (col & 15)) * 8) = v8;
    } else if (gid < 30720 + 7168) {          // highway: 2 x (16 k-groups x 224 n)
        int x = gid - 30720;
        const float* src = (x < 3584) ? hw1 : hw2;
        unsigned short* dst = (x < 3584) ? W1s : W2s;
        if (x >= 3584) x -= 3584;
        int kb = x / 224, n = x % 224, k0 = kb * 8;
        short8 v8;
#pragma unroll
        for (int i = 0; i < 8; ++i) {
            float v = (k0 + i < 112) ? src[n * 112 + k0 + i] : 0.f;
            v8[i] = (short)f2bf(v);
        }
        int q = kb >> 2, krh = kb & 3;
        *(short8*)(dst + q * 8192 + ((n >> 4) * 64 + krh * 16 + (n & 15)) * 8) = v8;
    } else if (gid < 30720 + 7168 + 8192) {   // proj: 16 k-groups x 512 n
        int x = gid - 37888;
        int kb = x / 512, n = x % 512, k0 = kb * 8;
        short8 v8;
#pragma unroll
        for (int i = 0; i < 8; ++i) {
            float v = (k0 + i < 112) ? pw[n * 112 + k0 + i] : 0.f;
            v8[i] = (short)f2bf(v);
        }
        int q = kb >> 2, krh = kb & 3;
        *(short8*)(Ps + ((q * 32 + (n >> 4)) * 64 + krh * 16 + (n & 15)) * 8) = v8;
    } else if (gid < 30720 + 7168 + 8192 + 1024) {  // zero W1/W2 pad tiles 14,15
        int x = gid - 46080;
        unsigned short* dst = (x < 512) ? W1s : W2s;
        x &= 511;
        int q = x >> 7, tt = 14 + ((x >> 6) & 1), e = x & 63;
        short8 z = {0, 0, 0, 0, 0, 0, 0, 0};
        *(short8*)(dst + q * 8192 + tt * 512 + e * 8) = z;
    }
}

// ===========================================================================
// Fused kernel: 512 thr / 8 waves / 64 rows / 512 blocks (2 per CU,
// 16 waves/CU -- first config above 8). Wave w: rg=w>>1 (rows rg*16..+15),
// cg=w&1 (column half). Conv acc 15 tiles/wave (60 VGPR), A streamed per
// chunk. Tail tiles cg-split with (proj,gate) pairs kept in-wave.
// LDS (64KB static): conv dbuf 2x32KB; then Cb[0,41216) f32 + ht@41216
// (64x136 shorts); then wb/pwb dbuf 2x16KB @[0,32768) + ht; epi4 ot 64KB.
// ===========================================================================
template <int T0, int NT>
__device__ __forceinline__ void dump_phase(float* Cb, const f32x4* acc, int cg, int rg, int lane) {
    int r0 = rg * 16 + ((lane >> 4) * 4);
    int c0 = lane & 15;
#pragma unroll
    for (int tt = 0; tt < NT; ++tt) {
        const int gt = T0 + tt;            // global tile: owner cg = gt/15
        if ((gt / 15) == cg) {
#pragma unroll
            for (int r = 0; r < 4; ++r)
                Cb[(r0 + r) * 161 + tt * 16 + c0] = acc[gt % 15][r];
        }
    }
}

__device__ void reduce_phase(const float* Cb, unsigned short* ht, int tid,
                             int cA, int NPA, int choffA, int colbA, const float* cbA,
                             int cB, int NPB, int choffB, int colbB, const float* cbB) {
    int noc = cA + cB;
    for (int idx = tid; idx < 64 * noc; idx += 512) {
        int row = idx & 63, ocp = idx >> 6;
        bool isB = ocp >= cA;
        int oc = isB ? ocp - cA : ocp;
        int NP = isB ? NPB : NPA;
        int colb = isB ? colbB : colbA;
        int choff = isB ? choffB : choffA;
        const float* cb = isB ? cbB : cbA;
        const float* src = Cb + row * 161 + colb + oc * NP;
        float m = src[0];
        for (int k = 1; k < NP; ++k) m = fmaxf(m, src[k]);
        float v = fmaxf(m + cb[oc], 0.f);
        ht[row * 136 + choff + oc] = f2bf(v);
    }
}

__global__ __launch_bounds__(512, 4) void fused_kernel(
        const float* __restrict__ feat, const unsigned short* __restrict__ WC,
        const float* cb0, const float* cb1, const float* cb2, const float* cb3,
        const float* cb4, const float* cb5, const float* cb6,
        const unsigned short* __restrict__ W1, const unsigned short* __restrict__ W2,
        const unsigned short* __restrict__ PW,
        const float* __restrict__ hb1, const float* __restrict__ hb2,
        const float* __restrict__ pb, float* __restrict__ out) {
    __shared__ __align__(16) char sm[65536];
    const int tid = threadIdx.x, lane = tid & 63, wave = tid >> 6;
    const int rg = wave >> 1, cg = wave & 1;
    const int c0 = lane & 15, kq = lane >> 4;
    const int m0 = blockIdx.x * 64;
    f32x4 zero = {0.f, 0.f, 0.f, 0.f};

    // ---------------- conv GEMM: acc 15 tiles/wave, A streamed ----------------
    const float* arow = feat + (size_t)(m0 + rg * 16 + c0) * KDIM + kq * 8;
    f32x4 acc[15];
#pragma unroll
    for (int t = 0; t < 15; ++t) acc[t] = zero;
    const int cgoff = cg * 15 * 1024;          // byte offset of this wave's tiles

    // prologue: stage chunk 0 into buf 0 (4 loads/thread)
    for (int i = tid; i < 2048; i += 512)
        stage16(WC + i * 8, sm + (i - lane) * 16, lane);

#pragma unroll
    for (int q = 0; q < 16; ++q) {
        // A-loads for chunk q FIRST (older than this iter's stage loads)
        float t0[4], t1[4];
        *(float4*)(t0) = *(const float4*)(arow + q * 32);
        *(float4*)(t1) = *(const float4*)(arow + q * 32 + 4);
        if (q < 15) {
            const unsigned short* src = WC + (q + 1) * 16384;
            char* dst = sm + ((q + 1) & 1) * BCHUNK;
            for (int i = tid; i < 2048; i += 512)
                stage16(src + i * 8, dst + (i - lane) * 16, lane);
            asm volatile("s_waitcnt vmcnt(4)" ::: "memory");   // chunk q + A_q landed
        } else {
            asm volatile("s_waitcnt vmcnt(0)" ::: "memory");
        }
        __builtin_amdgcn_s_barrier();
        short8 a;
#pragma unroll
        for (int i = 0; i < 4; ++i) { a[i] = (short)f2bf(t0[i]); a[4 + i] = (short)f2bf(t1[i]); }
        const char* bb = sm + (q & 1) * BCHUNK + cgoff;
        __builtin_amdgcn_s_setprio(1);
#pragma unroll
        for (int t = 0; t < 15; ++t) {
            short8 b = *(const short8*)(bb + t * 1024 + lane * 16);
            acc[t] = __builtin_amdgcn_mfma_f32_16x16x32_bf16(a, b, acc[t], 0, 0, 0);
        }
        __builtin_amdgcn_s_setprio(0);
        asm volatile("s_waitcnt lgkmcnt(0)" ::: "memory");     // buf reads done
        __builtin_amdgcn_s_barrier();                          // safe to restage
    }

    // ---------------- conv epilogue (max/bias/relu -> ht in LDS) ----------------
    float* Cb = (float*)sm;
    unsigned short* ht = (unsigned short*)(sm + 41216);   // 64 rows x 136 shorts
    for (int i = tid; i < 1024; i += 512)                 // zero K-pad cols 112..127
        ht[(i >> 4) * 136 + 112 + (i & 15)] = 0;
    dump_phase<0, 6>(Cb, acc, cg, rg, lane);
    asm volatile("s_waitcnt lgkmcnt(0)" ::: "memory");
    __builtin_amdgcn_s_barrier();
    reduce_phase(Cb, ht, tid, 4, 8, 0, 0, cb0, 8, 7, 4, 32, cb1);
    asm volatile("s_waitcnt lgkmcnt(0)" ::: "memory");
    __builtin_amdgcn_s_barrier();
    dump_phase<6, 10>(Cb, acc, cg, rg, lane);
    asm volatile("s_waitcnt lgkmcnt(0)" ::: "memory");
    __builtin_amdgcn_s_barrier();
    reduce_phase(Cb, ht, tid, 12, 6, 12, 0, cb2, 16, 5, 24, 80, cb3);
    asm volatile("s_waitcnt lgkmcnt(0)" ::: "memory");
    __builtin_amdgcn_s_barrier();
    dump_phase<16, 10>(Cb, acc, cg, rg, lane);
    asm volatile("s_waitcnt lgkmcnt(0)" ::: "memory");
    __builtin_amdgcn_s_barrier();
    reduce_phase(Cb, ht, tid, 20, 4, 40, 0, cb4, 24, 3, 60, 80, cb5);
    asm volatile("s_waitcnt lgkmcnt(0)" ::: "memory");
    __builtin_amdgcn_s_barrier();
    dump_phase<26, 4>(Cb, acc, cg, rg, lane);
    asm volatile("s_waitcnt lgkmcnt(0)" ::: "memory");
    __builtin_amdgcn_s_barrier();
    reduce_phase(Cb, ht, tid, 28, 2, 84, 0, cb6, 0, 1, 0, 0, cb6);
    asm volatile("s_waitcnt lgkmcnt(0)" ::: "memory");
    __builtin_amdgcn_s_barrier();                         // ht complete; Cb dead

    // tile-pair assignment for highway GEMMs (proj tile pt, gate tile pt+7;
    // cg1 j=3 uses zero-pad tiles 14/15 and is discarded in the epilogue)
    // ---------------- GEMM2 (highway1): 4 x 16KB dbuf chunks ----------------
    char* wb = sm;                                        // 2 x 16384
    short8 a2[4];
#pragma unroll
    for (int q = 0; q < 4; ++q)
        a2[q] = *(const short8*)((const char*)ht + (rg * 16 + c0) * 272 + q * 64 + kq * 16);
    for (int i = tid; i < 1024; i += 512)                 // stage W1 chunk 0
        stage16(W1 + i * 8, wb + (i - lane) * 16, lane);

    f32x4 p2[4], g2[4];
#pragma unroll
    for (int j = 0; j < 4; ++j) { p2[j] = zero; g2[j] = zero; }
#pragma unroll
    for (int q = 0; q < 4; ++q) {
        if (q < 3) {
            const unsigned short* src = W1 + (q + 1) * 8192;
            char* dst = wb + ((q + 1) & 1) * 16384;
            for (int i = tid; i < 1024; i += 512)
                stage16(src + i * 8, dst + (i - lane) * 16, lane);
        } else {
            for (int i = tid; i < 1024; i += 512)          // cross-prefetch W2 c0
                stage16(W2 + i * 8, wb + (i - lane) * 16, lane);
        }
        asm volatile("s_waitcnt vmcnt(2)" ::: "memory");
        __builtin_amdgcn_s_barrier();
        const char* bb = wb + (q & 1) * 16384;
#pragma unroll
        for (int j = 0; j < 4; ++j) {
            int pt = (cg == 0) ? j : ((j < 3) ? 4 + j : 14);
            int gt = (pt == 14) ? 15 : pt + 7;
            short8 bp = *(const short8*)(bb + pt * 1024 + lane * 16);
            short8 bg = *(const short8*)(bb + gt * 1024 + lane * 16);
            p2[j] = __builtin_amdgcn_mfma_f32_16x16x32_bf16(a2[q], bp, p2[j], 0, 0, 0);
            g2[j] = __builtin_amdgcn_mfma_f32_16x16x32_bf16(a2[q], bg, g2[j], 0, 0, 0);
        }
        asm volatile("s_waitcnt lgkmcnt(0)" ::: "memory");
        __builtin_amdgcn_s_barrier();
    }

    // epilogue2 -> ht (wave owns its tiles' cols; cross-cg barrier after)
#pragma unroll
    for (int j = 0; j < 4; ++j) {
        int pt = (cg == 0) ? j : ((j < 3) ? 4 + j : 14);
        if (pt < 7) {
            float bp = hb1[pt * 16 + c0], bg = hb1[112 + pt * 16 + c0];
#pragma unroll
            for (int r = 0; r < 4; ++r) {
                int row = rg * 16 + kq * 4 + r;
                int col = pt * 16 + c0;
                float px = p2[j][r] + bp;
                float gv = g2[j][r] + bg;
                float g = 1.f / (1.f + __expf(-gv));
                float hres = bf2f(ht[row * 136 + col]);
                ht[row * 136 + col] = f2bf(g * hres + (1.f - g) * fmaxf(px, 0.f));
            }
        }
    }
    asm volatile("s_waitcnt lgkmcnt(0)" ::: "memory");
    __builtin_amdgcn_s_barrier();                          // ht visible cross-cg

    // ---------------- GEMM3 (highway2): W2 chunks (c0 in flight) ----------------
    short8 a3[4];
#pragma unroll
    for (int q = 0; q < 4; ++q)
        a3[q] = *(const short8*)((const char*)ht + (rg * 16 + c0) * 272 + q * 64 + kq * 16);

    f32x4 p3[4], g3[4];
#pragma unroll
    for (int j = 0; j < 4; ++j) { p3[j] = zero; g3[j] = zero; }
#pragma unroll
    for (int q = 0; q < 4; ++q) {
        if (q < 3) {
            const unsigned short* src = W2 + (q + 1) * 8192;
            char* dst = wb + ((q + 1) & 1) * 16384;
            for (int i = tid; i < 1024; i += 512)
                stage16(src + i * 8, dst + (i - lane) * 16, lane);
        } else {
            for (int i = tid; i < 1024; i += 512)          // cross-prefetch PW c0
                stage16(PW + i * 8, wb + (i - lane) * 16, lane);
        }
        asm volatile("s_waitcnt vmcnt(2)" ::: "memory");
        __builtin_amdgcn_s_barrier();
        const char* bb = wb + (q & 1) * 16384;
#pragma unroll
        for (int j = 0; j < 4; ++j) {
            int pt = (cg == 0) ? j : ((j < 3) ? 4 + j : 14);
            int gt = (pt == 14) ? 15 : pt + 7;
            short8 bp = *(const short8*)(bb + pt * 1024 + lane * 16);
            short8 bg = *(const short8*)(bb + gt * 1024 + lane * 16);
            p3[j] = __builtin_amdgcn_mfma_f32_16x16x32_bf16(a3[q], bp, p3[j], 0, 0, 0);
            g3[j] = __builtin_amdgcn_mfma_f32_16x16x32_bf16(a3[q], bg, g3[j], 0, 0, 0);
        }
        asm volatile("s_waitcnt lgkmcnt(0)" ::: "memory");
        __builtin_amdgcn_s_barrier();
    }

    // epilogue3 -> ht
#pragma unroll
    for (int j = 0; j < 4; ++j) {
        int pt = (cg == 0) ? j : ((j < 3) ? 4 + j : 14);
        if (pt < 7) {
            float bp = hb2[pt * 16 + c0], bg = hb2[112 + pt * 16 + c0];
#pragma unroll
            for (int r = 0; r < 4; ++r) {
                int row = rg * 16 + kq * 4 + r;
                int col = pt * 16 + c0;
                float px = p3[j][r] + bp;
                float gv = g3[j][r] + bg;
                float g = 1.f / (1.f + __expf(-gv));
                float hres = bf2f(ht[row * 136 + col]);
                ht[row * 136 + col] = f2bf(g * hres + (1.f - g) * fmaxf(px, 0.f));
            }
        }
    }
    asm volatile("s_waitcnt lgkmcnt(0)" ::: "memory");
    __builtin_amdgcn_s_barrier();                          // ht visible cross-cg

    // ---------------- GEMM4 (proj): 8 x 16KB dbuf chunks, 8 tiles/wave ----------------
    short8 a4[4];
#pragma unroll
    for (int q = 0; q < 4; ++q)
        a4[q] = *(const short8*)((const char*)ht + (rg * 16 + c0) * 272 + q * 64 + kq * 16);

    char* pwb = sm;                                       // 2 x 16384 (buf0 = PW c0)
    f32x4 acc4[16];
#pragma unroll
    for (int t = 0; t < 16; ++t) acc4[t] = zero;
#pragma unroll
    for (int c = 0; c < 8; ++c) {
        if (c < 7) {
            const unsigned short* src = PW + (c + 1) * 8192;
            char* dst = pwb + ((c + 1) & 1) * 16384;
            for (int i = tid; i < 1024; i += 512)
                stage16(src + i * 8, dst + (i - lane) * 16, lane);
            asm volatile("s_waitcnt vmcnt(2)" ::: "memory");
        } else {
            asm volatile("s_waitcnt vmcnt(0)" ::: "memory");
        }
        __builtin_amdgcn_s_barrier();
        const char* bb = pwb + (c & 1) * 16384;
        __builtin_amdgcn_s_setprio(1);
#pragma unroll
        for (int j = 0; j < 8; ++j) {
            int tt = cg * 8 + j;
            short8 b = *(const short8*)(bb + tt * 1024 + lane * 16);
            int ai = (c & 1) * 8 + j;
            acc4[ai] = __builtin_amdgcn_mfma_f32_16x16x32_bf16(a4[c >> 1], b, acc4[ai], 0, 0, 0);
        }
        __builtin_amdgcn_s_setprio(0);
        asm volatile("s_waitcnt lgkmcnt(0)" ::: "memory");
        __builtin_amdgcn_s_barrier();
    }

    // ---------------- epilogue4: +bias, coalesced store via LDS transpose ----------------
    float* ot = (float*)sm;
#pragma unroll
    for (int h = 0; h < 2; ++h) {
        __syncthreads();
#pragma unroll
        for (int j = 0; j < 8; ++j) {
            int tt = cg * 8 + j;
            int col = (h * 16 + tt) * 16 + c0;
            float b = pb[col];
#pragma unroll
            for (int r = 0; r < 4; ++r)
                ot[(rg * 16 + kq * 4 + r) * 256 + tt * 16 + c0] = acc4[h * 8 + j][r] + b;
        }
        __syncthreads();
        for (int i = tid; i < 4096; i += 512) {
            int row = i >> 6, cc = i & 63;
            *(float4*)(out + (size_t)(m0 + row) * 512 + h * 256 + cc * 4) = ((const float4*)ot)[i];
        }
    }
}

// ===========================================================================
extern "C" void kernel_launch(void* const* d_in, const int* in_sizes, int n_in,
                              void* d_out, int out_size, void* d_ws, size_t ws_size,
                              hipStream_t stream) {
    const float* feat = (const float*)d_in[0];
    const float* cw[7];
    const float* cb[7];
    for (int f = 0; f < 7; ++f) {
        cw[f] = (const float*)d_in[1 + 2 * f];
        cb[f] = (const float*)d_in[2 + 2 * f];
    }
    const float* hw_w1 = (const float*)d_in[15];
    const float* hw_b1 = (const float*)d_in[16];
    const float* hw_w2 = (const float*)d_in[17];
    const float* hw_b2 = (const float*)d_in[18];
    const float* pw    = (const float*)d_in[19];
    const float* pb    = (const float*)d_in[20];
    float* out = (float*)d_out;

    char* ws = (char*)d_ws;
    unsigned short* WC  = (unsigned short*)ws;                  // 524,288 B (16 x 32KB padded)
    unsigned short* W1s = (unsigned short*)(ws + 524288);       //  65,536 B (4 x 16KB, 16 tiles)
    unsigned short* W2s = (unsigned short*)(ws + 589824);       //  65,536 B
    unsigned short* Ps  = (unsigned short*)(ws + 655360);       // 131,072 B (8 x 16KB)

    prep_kernel<<<184, 256, 0, stream>>>(cw[0], cw[1], cw[2], cw[3], cw[4], cw[5], cw[6],
                                         hw_w1, hw_w2, pw, WC, W1s, W2s, Ps);
    fused_kernel<<<512, 512, 0, stream>>>(feat, WC, cb[0], cb[1], cb[2], cb[3], cb[4], cb[5], cb[6],
                                          W1s, W2s, Ps, hw_b1, hw_b2, pb, out);
}